// Round 3
// baseline (107.285 us; speedup 1.0000x reference)
//
#include <hip/hip_runtime.h>

// NAM forward, table-based (round 5b — fixes round-2 compile error:
// __builtin_nontemporal_load rejects HIP_vector_type float4; use a clang
// ext_vector_type(4) float instead, identical layout). Each feature's MLP
// (1->64->32->1) is piecewise-linear in one scalar x_f -> tabulate
// contribution_f, lerp per sample. Round-4 -> round-5:
//   * build: each node evaluated ONCE (adjacent cells share nodes; v1 of cell
//     i == v0 of cell i+1). 129 nodes per 128-cell block, shared via LDS.
//   * build: per-node 64-h chain split across 2 thread halves (h 0..31 /
//     32..63); partial acc[32] merged through LDS (row stride 33 floats ->
//     bank-conflict-free b32). Halves are 192-thread (3-wave) aligned so
//     `half` and all weight indices stay wave-uniform -> W2 stays s_load.
//     Serial chain ~4480 -> ~1150 VALU instrs: build ~3.7us -> ~1.0us.
//   * eval: nontemporal hints on the 17.8MB x stream + out store so the
//     139KB table stays L2-resident for the gathers.
// Remaining time is dominated by harness overhead (268MB d_ws poison fill
// ~44us + input restores + stream-op gaps ~ 85-90us floor).

typedef float f32x4 __attribute__((ext_vector_type(4)));  // native vec: nt-load ok

constexpr int B_TOT = 262144;
constexpr int F     = 17;
constexpr int H1N   = 64;
constexpr int H2N   = 32;
constexpr int BLK   = 256;

constexpr int   NCELLS = 1024;            // 2^10 cells
constexpr float XMIN   = -8.0f;
constexpr float SCALE  = 64.0f;           // cells per unit x; grid [-8, 8)

// build geometry
constexpr int CELLS_PB = 128;             // cells per block
constexpr int NODES_PB = CELLS_PB + 1;    // 129 node evals per block
constexpr int HALF_T   = 192;             // 3 waves per h-half
constexpr int BUILD_T  = 2 * HALF_T;      // 384 threads

// ---- kernel 1: build per-cell (value, delta), node-shared + h-split --------
__global__ __launch_bounds__(BUILD_T)
void build_pairs_split(const float* __restrict__ W1, const float* __restrict__ b1,
                       const float* __restrict__ W2, const float* __restrict__ b2,
                       const float* __restrict__ W3, const float* __restrict__ b3,
                       float2* __restrict__ pairs)
{
    __shared__ float part[NODES_PB][H2N + 1];   // +1 pad: 132B rows, banks (nl+k)%32
    __shared__ float vnode[NODES_PB];

    const int f    = blockIdx.y;                 // wave-uniform -> s_loads
    const int t    = threadIdx.x;
    const int half = (t >= HALF_T) ? 1 : 0;      // wave-uniform (192 = 3 waves)
    const int nl   = t - half * HALF_T;          // local node index
    const bool act = nl < NODES_PB;

    const float* __restrict__ w1f = W1 + f * H1N;
    const float* __restrict__ bb1 = b1 + f * H1N;
    const float* __restrict__ w2f = W2 + f * H1N * H2N;
    const float* __restrict__ bb2 = b2 + f * H2N;

    const int   ni = blockIdx.x * CELLS_PB + nl; // node index (inactive: junk, unused)
    const float xv = (float)ni * (1.0f / SCALE) + XMIN;

    float acc[H2N];
    #pragma unroll
    for (int o = 0; o < H2N; ++o) acc[o] = (half == 0) ? bb2[o] : 0.0f;

    const int hb = half * (H1N / 2);
    #pragma unroll 4
    for (int hh = 0; hh < H1N / 2; ++hh) {
        const int h = hb + hh;
        const float h1v = fmaxf(fmaf(xv, w1f[h], bb1[h]), 0.0f);
        const float* __restrict__ w2h = w2f + h * H2N;
        #pragma unroll
        for (int o = 0; o < H2N; ++o)
            acc[o] = fmaf(h1v, w2h[o], acc[o]);
    }

    if (half == 1 && act) {
        #pragma unroll
        for (int o = 0; o < H2N; ++o) part[nl][o] = acc[o];
    }
    __syncthreads();

    if (half == 0 && act) {
        const float* __restrict__ w3f = W3 + f * H2N;
        float contrib = b3[f];
        #pragma unroll
        for (int o = 0; o < H2N; ++o)
            contrib = fmaf(fmaxf(acc[o] + part[nl][o], 0.0f), w3f[o], contrib);
        vnode[nl] = contrib;
    }
    __syncthreads();

    if (t < CELLS_PB) {
        const float v0 = vnode[t];
        const float v1 = vnode[t + 1];
        pairs[f * NCELLS + blockIdx.x * CELLS_PB + t] = make_float2(v0, v1 - v0);
    }
}

// ---- kernel 2: per-sample lerp + sum ---------------------------------------
__global__ __launch_bounds__(BLK)
void eval_nam(const float* __restrict__ x, const float* __restrict__ bias,
              const float2* __restrict__ pairs, float* __restrict__ out)
{
    __shared__ float xs[BLK * F];                   // stride 17 (odd): 2-way, free
    const int tid  = threadIdx.x;
    const int base = blockIdx.x * BLK;

    // BLK*F = 4352 floats = 1088 x 16B, coalesced 16B/lane, nt: don't churn L2
    const f32x4* xblk4 = (const f32x4*)(x + (size_t)base * F);
    f32x4* xs4 = (f32x4*)xs;
    #pragma unroll
    for (int k = tid; k < BLK * F / 4; k += BLK)
        xs4[k] = __builtin_nontemporal_load(&xblk4[k]);
    __syncthreads();

    float score = bias[0];
    #pragma unroll
    for (int f = 0; f < F; ++f) {
        const float xv   = xs[tid * F + f];
        const float pos  = (xv - XMIN) * SCALE;
        int i = (int)pos;                           // trunc; clamped next
        i = max(0, min(i, NCELLS - 1));
        const float frac = pos - (float)i;          // <0 or >1 => linear extrap
        const float2 p   = pairs[(f << 10) + i];
        score = fmaf(p.y, frac, score + p.x);
    }
    __builtin_nontemporal_store(score, &out[base + tid]);
}

// ---- fallback: direct kernel (used only if ws too small) -------------------
__device__ __forceinline__
float mlp_eval(float xv,
               const float* __restrict__ w1f, const float* __restrict__ bb1,
               const float* __restrict__ w2f, const float* __restrict__ bb2,
               const float* __restrict__ w3f, float b3f)
{
    float acc[H2N];
    #pragma unroll
    for (int o = 0; o < H2N; ++o) acc[o] = bb2[o];
    #pragma unroll 4
    for (int h = 0; h < H1N; ++h) {
        const float h1v = fmaxf(fmaf(xv, w1f[h], bb1[h]), 0.0f);
        const float* __restrict__ w2h = w2f + h * H2N;
        #pragma unroll
        for (int o = 0; o < H2N; ++o)
            acc[o] = fmaf(h1v, w2h[o], acc[o]);
    }
    float contrib = b3f;
    #pragma unroll
    for (int o = 0; o < H2N; ++o)
        contrib = fmaf(fmaxf(acc[o], 0.0f), w3f[o], contrib);
    return contrib;
}

__global__ __launch_bounds__(BLK)
void nam_fwd(const float* __restrict__ x,
             const float* __restrict__ W1, const float* __restrict__ b1,
             const float* __restrict__ W2, const float* __restrict__ b2,
             const float* __restrict__ W3, const float* __restrict__ b3,
             const float* __restrict__ bias, float* __restrict__ out)
{
    __shared__ float xs[BLK * F];
    const int tid  = threadIdx.x;
    const int base = blockIdx.x * BLK;
    const float* xblk = x + (size_t)base * F;
    #pragma unroll
    for (int i = tid; i < BLK * F; i += BLK) xs[i] = xblk[i];
    __syncthreads();

    float score = bias[0];
    for (int f = 0; f < F; ++f) {
        const float xv = xs[tid * F + f];
        score += mlp_eval(xv, W1 + f * H1N, b1 + f * H1N,
                          W2 + f * H1N * H2N, b2 + f * H2N,
                          W3 + f * H2N, b3[f]);
    }
    out[base + tid] = score;
}

extern "C" void kernel_launch(void* const* d_in, const int* in_sizes, int n_in,
                              void* d_out, int out_size, void* d_ws, size_t ws_size,
                              hipStream_t stream)
{
    const float* x    = (const float*)d_in[0];
    const float* W1   = (const float*)d_in[1];
    const float* b1   = (const float*)d_in[2];
    const float* W2   = (const float*)d_in[3];
    const float* b2   = (const float*)d_in[4];
    const float* W3   = (const float*)d_in[5];
    const float* b3   = (const float*)d_in[6];
    const float* bias = (const float*)d_in[7];
    float* out = (float*)d_out;

    const size_t pairs_bytes = (size_t)F * NCELLS * sizeof(float2);  // 139 KB

    if (ws_size >= pairs_bytes) {
        float2* pairs = (float2*)d_ws;                         // 8B-aligned at 0

        dim3 gb(NCELLS / CELLS_PB, F);                         // 8 x 17 blocks
        build_pairs_split<<<gb, BUILD_T, 0, stream>>>(W1, b1, W2, b2, W3, b3, pairs);

        eval_nam<<<B_TOT / BLK, BLK, 0, stream>>>(x, bias, pairs, out);
    } else {
        // ws too small for tables (call-invariant condition): direct eval
        nam_fwd<<<B_TOT / BLK, BLK, 0, stream>>>(x, W1, b1, W2, b2, W3, b3,
                                                 bias, out);
    }
}

// Round 4
// 104.266 us; speedup vs baseline: 1.0290x; 1.0290x over previous
//
#include <hip/hip_runtime.h>

// NAM forward, table-based (round 6). Each feature's MLP (1->64->32->1) is
// piecewise-linear in one scalar x_f -> tabulate contribution_f, lerp per
// sample. Round-5 -> round-6:
//   * REVERT the nontemporal load/store hints from eval_nam (round-3 bench:
//     97.7 -> 107.3us regression; nt no-allocate policy forfeits L2/L3 hits
//     on the freshly-restored x stream — unexplained 10us => revert).
//     eval_nam is byte-identical to the 97.7us round-0 version.
//   * KEEP the round-5 build rewrite: each node evaluated ONCE (adjacent
//     cells share nodes; v1 of cell i == v0 of cell i+1), 129 nodes per
//     128-cell block; per-node 64-h chain split across 2 thread halves
//     (h 0..31 / 32..63), partials merged via LDS (row stride 33 floats ->
//     conflict-free). Halves are 192-thread (3-wave) aligned so `half` and
//     weight indices stay wave-uniform -> W2 stays s_load. Serial chain
//     ~4480 -> ~1150 VALU instrs: build ~3.7us -> ~1.2us.
// Remaining time is dominated by harness overhead (268MB d_ws poison fill
// ~44us + input restores + stream-op gaps ~ 85-90us floor).

constexpr int B_TOT = 262144;
constexpr int F     = 17;
constexpr int H1N   = 64;
constexpr int H2N   = 32;
constexpr int BLK   = 256;

constexpr int   NCELLS = 1024;            // 2^10 cells
constexpr float XMIN   = -8.0f;
constexpr float SCALE  = 64.0f;           // cells per unit x; grid [-8, 8)

// build geometry
constexpr int CELLS_PB = 128;             // cells per block
constexpr int NODES_PB = CELLS_PB + 1;    // 129 node evals per block
constexpr int HALF_T   = 192;             // 3 waves per h-half
constexpr int BUILD_T  = 2 * HALF_T;      // 384 threads

// ---- kernel 1: build per-cell (value, delta), node-shared + h-split --------
__global__ __launch_bounds__(BUILD_T)
void build_pairs_split(const float* __restrict__ W1, const float* __restrict__ b1,
                       const float* __restrict__ W2, const float* __restrict__ b2,
                       const float* __restrict__ W3, const float* __restrict__ b3,
                       float2* __restrict__ pairs)
{
    __shared__ float part[NODES_PB][H2N + 1];   // +1 pad: 132B rows, banks (nl+k)%32
    __shared__ float vnode[NODES_PB];

    const int f    = blockIdx.y;                 // wave-uniform -> s_loads
    const int t    = threadIdx.x;
    const int half = (t >= HALF_T) ? 1 : 0;      // wave-uniform (192 = 3 waves)
    const int nl   = t - half * HALF_T;          // local node index
    const bool act = nl < NODES_PB;

    const float* __restrict__ w1f = W1 + f * H1N;
    const float* __restrict__ bb1 = b1 + f * H1N;
    const float* __restrict__ w2f = W2 + f * H1N * H2N;
    const float* __restrict__ bb2 = b2 + f * H2N;

    const int   ni = blockIdx.x * CELLS_PB + nl; // node index (inactive: junk, unused)
    const float xv = (float)ni * (1.0f / SCALE) + XMIN;

    float acc[H2N];
    #pragma unroll
    for (int o = 0; o < H2N; ++o) acc[o] = (half == 0) ? bb2[o] : 0.0f;

    const int hb = half * (H1N / 2);
    #pragma unroll 4
    for (int hh = 0; hh < H1N / 2; ++hh) {
        const int h = hb + hh;
        const float h1v = fmaxf(fmaf(xv, w1f[h], bb1[h]), 0.0f);
        const float* __restrict__ w2h = w2f + h * H2N;
        #pragma unroll
        for (int o = 0; o < H2N; ++o)
            acc[o] = fmaf(h1v, w2h[o], acc[o]);
    }

    if (half == 1 && act) {
        #pragma unroll
        for (int o = 0; o < H2N; ++o) part[nl][o] = acc[o];
    }
    __syncthreads();

    if (half == 0 && act) {
        const float* __restrict__ w3f = W3 + f * H2N;
        float contrib = b3[f];
        #pragma unroll
        for (int o = 0; o < H2N; ++o)
            contrib = fmaf(fmaxf(acc[o] + part[nl][o], 0.0f), w3f[o], contrib);
        vnode[nl] = contrib;
    }
    __syncthreads();

    if (t < CELLS_PB) {
        const float v0 = vnode[t];
        const float v1 = vnode[t + 1];
        pairs[f * NCELLS + blockIdx.x * CELLS_PB + t] = make_float2(v0, v1 - v0);
    }
}

// ---- kernel 2: per-sample lerp + sum (round-0 form, no nt hints) -----------
__global__ __launch_bounds__(BLK)
void eval_nam(const float* __restrict__ x, const float* __restrict__ bias,
              const float2* __restrict__ pairs, float* __restrict__ out)
{
    __shared__ float xs[BLK * F];                   // stride 17 (odd): 2-way, free
    const int tid  = threadIdx.x;
    const int base = blockIdx.x * BLK;

    // BLK*F = 4352 floats = 1088 float4, coalesced 16B/lane
    const float4* xblk4 = (const float4*)(x + (size_t)base * F);
    float4* xs4 = (float4*)xs;
    #pragma unroll
    for (int k = tid; k < BLK * F / 4; k += BLK) xs4[k] = xblk4[k];
    __syncthreads();

    float score = bias[0];
    #pragma unroll
    for (int f = 0; f < F; ++f) {
        const float xv   = xs[tid * F + f];
        const float pos  = (xv - XMIN) * SCALE;
        int i = (int)pos;                           // trunc; clamped next
        i = max(0, min(i, NCELLS - 1));
        const float frac = pos - (float)i;          // <0 or >1 => linear extrap
        const float2 p   = pairs[(f << 10) + i];
        score = fmaf(p.y, frac, score + p.x);
    }
    out[base + tid] = score;
}

// ---- fallback: direct kernel (used only if ws too small) -------------------
__device__ __forceinline__
float mlp_eval(float xv,
               const float* __restrict__ w1f, const float* __restrict__ bb1,
               const float* __restrict__ w2f, const float* __restrict__ bb2,
               const float* __restrict__ w3f, float b3f)
{
    float acc[H2N];
    #pragma unroll
    for (int o = 0; o < H2N; ++o) acc[o] = bb2[o];
    #pragma unroll 4
    for (int h = 0; h < H1N; ++h) {
        const float h1v = fmaxf(fmaf(xv, w1f[h], bb1[h]), 0.0f);
        const float* __restrict__ w2h = w2f + h * H2N;
        #pragma unroll
        for (int o = 0; o < H2N; ++o)
            acc[o] = fmaf(h1v, w2h[o], acc[o]);
    }
    float contrib = b3f;
    #pragma unroll
    for (int o = 0; o < H2N; ++o)
        contrib = fmaf(fmaxf(acc[o], 0.0f), w3f[o], contrib);
    return contrib;
}

__global__ __launch_bounds__(BLK)
void nam_fwd(const float* __restrict__ x,
             const float* __restrict__ W1, const float* __restrict__ b1,
             const float* __restrict__ W2, const float* __restrict__ b2,
             const float* __restrict__ W3, const float* __restrict__ b3,
             const float* __restrict__ bias, float* __restrict__ out)
{
    __shared__ float xs[BLK * F];
    const int tid  = threadIdx.x;
    const int base = blockIdx.x * BLK;
    const float* xblk = x + (size_t)base * F;
    #pragma unroll
    for (int i = tid; i < BLK * F; i += BLK) xs[i] = xblk[i];
    __syncthreads();

    float score = bias[0];
    for (int f = 0; f < F; ++f) {
        const float xv = xs[tid * F + f];
        score += mlp_eval(xv, W1 + f * H1N, b1 + f * H1N,
                          W2 + f * H1N * H2N, b2 + f * H2N,
                          W3 + f * H2N, b3[f]);
    }
    out[base + tid] = score;
}

extern "C" void kernel_launch(void* const* d_in, const int* in_sizes, int n_in,
                              void* d_out, int out_size, void* d_ws, size_t ws_size,
                              hipStream_t stream)
{
    const float* x    = (const float*)d_in[0];
    const float* W1   = (const float*)d_in[1];
    const float* b1   = (const float*)d_in[2];
    const float* W2   = (const float*)d_in[3];
    const float* b2   = (const float*)d_in[4];
    const float* W3   = (const float*)d_in[5];
    const float* b3   = (const float*)d_in[6];
    const float* bias = (const float*)d_in[7];
    float* out = (float*)d_out;

    const size_t pairs_bytes = (size_t)F * NCELLS * sizeof(float2);  // 139 KB

    if (ws_size >= pairs_bytes) {
        float2* pairs = (float2*)d_ws;                         // 8B-aligned at 0

        dim3 gb(NCELLS / CELLS_PB, F);                         // 8 x 17 blocks
        build_pairs_split<<<gb, BUILD_T, 0, stream>>>(W1, b1, W2, b2, W3, b3, pairs);

        eval_nam<<<B_TOT / BLK, BLK, 0, stream>>>(x, bias, pairs, out);
    } else {
        // ws too small for tables (call-invariant condition): direct eval
        nam_fwd<<<B_TOT / BLK, BLK, 0, stream>>>(x, W1, b1, W2, b2, W3, b3,
                                                 bias, out);
    }
}

// Round 5
// 98.564 us; speedup vs baseline: 1.0885x; 1.0579x over previous
//
#include <hip/hip_runtime.h>

// NAM forward, table-based (round 7 = EXACT revert to the round-0 source that
// measured 97.7us / 98.5us). Each feature's MLP (1->64->32->1) is
// piecewise-linear in one scalar x_f -> tabulate contribution_f, lerp per
// sample.
// A/B ledger: {old build, old eval} = 97.7 | {new build, old eval} = 104.3 |
// {new build, nt eval} = 107.3. The build rewrite cannot arithmetically cost
// 6.5us (136 blocks, <=2us either way), so this run decides: ~104 => session
// noise on the ~90us harness floor (poison fill 43us + restores + gaps) and
// we are at the floor; ~98 => old build is empirically faster and stays.
//   * build_v + build_pairs merged: one kernel computes both cell endpoints
//     exactly and writes (v0, v1-v0) float2 directly (2x node evals, trivial).
//   * NCELLS 1024 (h = 1/64): hot +-2sigma table set ~35KB ~ L1.
// Remaining time is dominated by harness overhead (268MB d_ws poison fill
// ~44us + input restores + stream-op gaps ~ 85-90us floor).

constexpr int B_TOT = 262144;
constexpr int F     = 17;
constexpr int H1N   = 64;
constexpr int H2N   = 32;
constexpr int BLK   = 256;

constexpr int   NCELLS = 1024;            // 2^10 cells
constexpr float XMIN   = -8.0f;
constexpr float SCALE  = 64.0f;           // cells per unit x; grid [-8, 8)

// Exact MLP eval for one feature at one scalar x (weights wave-uniform).
__device__ __forceinline__
float mlp_eval(float xv,
               const float* __restrict__ w1f, const float* __restrict__ bb1,
               const float* __restrict__ w2f, const float* __restrict__ bb2,
               const float* __restrict__ w3f, float b3f)
{
    float acc[H2N];
    #pragma unroll
    for (int o = 0; o < H2N; ++o) acc[o] = bb2[o];
    #pragma unroll 4
    for (int h = 0; h < H1N; ++h) {
        const float h1v = fmaxf(fmaf(xv, w1f[h], bb1[h]), 0.0f);
        const float* __restrict__ w2h = w2f + h * H2N;
        #pragma unroll
        for (int o = 0; o < H2N; ++o)
            acc[o] = fmaf(h1v, w2h[o], acc[o]);
    }
    float contrib = b3f;
    #pragma unroll
    for (int o = 0; o < H2N; ++o)
        contrib = fmaf(fmaxf(acc[o], 0.0f), w3f[o], contrib);
    return contrib;
}

// ---- kernel 1: build per-cell (value, delta) directly ----------------------
__global__ __launch_bounds__(128)
void build_pairs_direct(const float* __restrict__ W1, const float* __restrict__ b1,
                        const float* __restrict__ W2, const float* __restrict__ b2,
                        const float* __restrict__ W3, const float* __restrict__ b3,
                        float2* __restrict__ pairs)
{
    const int f = blockIdx.y;                       // wave-uniform -> s_loads
    const int i = blockIdx.x * blockDim.x + threadIdx.x;
    if (i >= NCELLS) return;

    const float* __restrict__ w1f = W1 + f * H1N;
    const float* __restrict__ bb1 = b1 + f * H1N;
    const float* __restrict__ w2f = W2 + f * H1N * H2N;
    const float* __restrict__ bb2 = b2 + f * H2N;
    const float* __restrict__ w3f = W3 + f * H2N;
    const float  b3f = b3[f];

    const float x0 = (float)i       * (1.0f / SCALE) + XMIN;
    const float x1 = (float)(i + 1) * (1.0f / SCALE) + XMIN;
    const float v0 = mlp_eval(x0, w1f, bb1, w2f, bb2, w3f, b3f);
    const float v1 = mlp_eval(x1, w1f, bb1, w2f, bb2, w3f, b3f);

    pairs[f * NCELLS + i] = make_float2(v0, v1 - v0);
}

// ---- kernel 2: per-sample lerp + sum ---------------------------------------
__global__ __launch_bounds__(BLK)
void eval_nam(const float* __restrict__ x, const float* __restrict__ bias,
              const float2* __restrict__ pairs, float* __restrict__ out)
{
    __shared__ float xs[BLK * F];                   // stride 17 (odd): 2-way, free
    const int tid  = threadIdx.x;
    const int base = blockIdx.x * BLK;

    // BLK*F = 4352 floats = 1088 float4, coalesced 16B/lane
    const float4* xblk4 = (const float4*)(x + (size_t)base * F);
    float4* xs4 = (float4*)xs;
    #pragma unroll
    for (int k = tid; k < BLK * F / 4; k += BLK) xs4[k] = xblk4[k];
    __syncthreads();

    float score = bias[0];
    #pragma unroll
    for (int f = 0; f < F; ++f) {
        const float xv   = xs[tid * F + f];
        const float pos  = (xv - XMIN) * SCALE;
        int i = (int)pos;                           // trunc; clamped next
        i = max(0, min(i, NCELLS - 1));
        const float frac = pos - (float)i;          // <0 or >1 => linear extrap
        const float2 p   = pairs[(f << 10) + i];
        score = fmaf(p.y, frac, score + p.x);
    }
    out[base + tid] = score;
}

// ---- fallback: direct kernel (used only if ws too small) -------------------
__global__ __launch_bounds__(BLK)
void nam_fwd(const float* __restrict__ x,
             const float* __restrict__ W1, const float* __restrict__ b1,
             const float* __restrict__ W2, const float* __restrict__ b2,
             const float* __restrict__ W3, const float* __restrict__ b3,
             const float* __restrict__ bias, float* __restrict__ out)
{
    __shared__ float xs[BLK * F];
    const int tid  = threadIdx.x;
    const int base = blockIdx.x * BLK;
    const float* xblk = x + (size_t)base * F;
    #pragma unroll
    for (int i = tid; i < BLK * F; i += BLK) xs[i] = xblk[i];
    __syncthreads();

    float score = bias[0];
    for (int f = 0; f < F; ++f) {
        const float xv = xs[tid * F + f];
        score += mlp_eval(xv, W1 + f * H1N, b1 + f * H1N,
                          W2 + f * H1N * H2N, b2 + f * H2N,
                          W3 + f * H2N, b3[f]);
    }
    out[base + tid] = score;
}

extern "C" void kernel_launch(void* const* d_in, const int* in_sizes, int n_in,
                              void* d_out, int out_size, void* d_ws, size_t ws_size,
                              hipStream_t stream)
{
    const float* x    = (const float*)d_in[0];
    const float* W1   = (const float*)d_in[1];
    const float* b1   = (const float*)d_in[2];
    const float* W2   = (const float*)d_in[3];
    const float* b2   = (const float*)d_in[4];
    const float* W3   = (const float*)d_in[5];
    const float* b3   = (const float*)d_in[6];
    const float* bias = (const float*)d_in[7];
    float* out = (float*)d_out;

    const size_t pairs_bytes = (size_t)F * NCELLS * sizeof(float2);  // 139 KB

    if (ws_size >= pairs_bytes) {
        float2* pairs = (float2*)d_ws;                         // 8B-aligned at 0

        dim3 gb((NCELLS + 127) / 128, F);                      // 8 x 17 blocks
        build_pairs_direct<<<gb, 128, 0, stream>>>(W1, b1, W2, b2, W3, b3, pairs);

        eval_nam<<<B_TOT / BLK, BLK, 0, stream>>>(x, bias, pairs, out);
    } else {
        // ws too small for tables (call-invariant condition): direct eval
        nam_fwd<<<B_TOT / BLK, BLK, 0, stream>>>(x, W1, b1, W2, b2, W3, b3,
                                                 bias, out);
    }
}